// Round 12
// baseline (1088.699 us; speedup 1.0000x reference)
//
#include <hip/hip_runtime.h>
#include <hip/hip_cooperative_groups.h>
namespace cg = cooperative_groups;

#define TTOK 8192   // B*L
#define BATCH 4
#define LSEQ 2048
#define NDM 256
#define NF 128
#define NDI 512
#define NDS 16
#define NDR 16
#define CHUNK 16
#define NCH (LSEQ / CHUNK)   // 128
#define NCH_LOG 7

typedef unsigned short u16;
typedef __attribute__((ext_vector_type(8))) short bf16x8;
typedef __attribute__((ext_vector_type(4))) float f32x4;

__device__ __forceinline__ float sigmoidf_(float x) { return 1.f / (1.f + __expf(-x)); }

__device__ __forceinline__ u16 f2bf(float f) {  // RTN-even
  unsigned u = __float_as_uint(f);
  u += 0x7FFF + ((u >> 16) & 1);
  return (u16)(u >> 16);
}
__device__ __forceinline__ float bf2f(u16 v) {
  return __uint_as_float((unsigned)v << 16);
}
__device__ __forceinline__ float softplus_(float x) {  // stable
  return fmaxf(x, 0.f) + __logf(1.f + __expf(-fabsf(x)));
}

// ---------------- bf16 MFMA GEMM ----------------
// C = A·W^T (+bias) (+= if RES). A:[M][K] bf16, W:[N][K] bf16.
// Tile BM_T x BN_T, BK=64, 4 waves. NCHK: clamp W rows / skip cols >= N.
// EPI: 0 = f32 out. 1 = bf16 out (+bf16 residual if RES) + per-row ssq
//      atomicAdd into rssq. 2 = "RMS": scale by rsqrt(rssq[r]/256+eps), bf16
//      out. 3 = bf16 out (+bf16 residual), plain.
template<int BM_T, int BN_T, bool BIAS, bool RES, bool NCHK, int EPI>
__global__ __launch_bounds__(256) void gemm_bf16(const u16* __restrict__ A,
                                                 const u16* __restrict__ W,
                                                 const float* __restrict__ bias,
                                                 void* __restrict__ Cv,
                                                 int N, int K,
                                                 float* __restrict__ rssq) {
  constexpr int WR = BM_T / 64;
  constexpr int WC = 4 / WR;
  constexpr int NR = BN_T / (16 * WC);
  constexpr int ROWS = BM_T + BN_T;
  constexpr int CPW = ROWS / 32;
  __shared__ u16 lds[ROWS * 64];
  const int tid = threadIdx.x;
  const int wave = tid >> 6, lane = tid & 63;
  const int wrow = wave / WC, wcol = wave % WC;
  const int lr = lane & 15, lg = lane >> 4;
  const int row0 = blockIdx.y * BM_T, col0 = blockIdx.x * BN_T;

  const u16* srcp[CPW];
  u16* ldsp[CPW];
#pragma unroll
  for (int i = 0; i < CPW; ++i) {
    const int q = wave * CPW + i;
    const int row = q * 8 + (lane >> 3);
    const int ck = lane & 7;
    const int sck = ck ^ (row & 7);
    long grow;
    if (row < BM_T) grow = (long)(row0 + row) * K;
    else {
      int wr = row - BM_T;
      if (NCHK && wr >= N) wr = N - 1;
      grow = (long)(col0 + wr) * K;
    }
    srcp[i] = ((row < BM_T) ? A : W) + grow + sck * 8;
    ldsp[i] = (u16*)&lds[q * 512];
  }

  int aoff[4], as7[4], boff[NR], bs7[NR];
#pragma unroll
  for (int m = 0; m < 4; ++m) {
    const int r = wrow * 64 + m * 16 + lr;
    aoff[m] = r * 64; as7[m] = r & 7;
  }
#pragma unroll
  for (int n = 0; n < NR; ++n) {
    const int r = BM_T + wcol * (BN_T / WC) + n * 16 + lr;
    boff[n] = r * 64; bs7[n] = r & 7;
  }

  f32x4 acc[4][NR];
#pragma unroll
  for (int m = 0; m < 4; ++m)
#pragma unroll
    for (int n = 0; n < NR; ++n) acc[m][n] = (f32x4)(0.f);

  for (int k0 = 0; k0 < K; k0 += 64) {
#pragma unroll
    for (int i = 0; i < CPW; ++i)
      __builtin_amdgcn_global_load_lds(
          (const __attribute__((address_space(1))) unsigned int*)(srcp[i] + k0),
          (__attribute__((address_space(3))) unsigned int*)(ldsp[i]), 16, 0, 0);
    __syncthreads();

    bf16x8 af[2][4], bfr[2][NR];
#pragma unroll
    for (int kq = 0; kq < 2; ++kq) {
      const int kc = kq * 4 + lg;
#pragma unroll
      for (int m = 0; m < 4; ++m)
        af[kq][m] = *(const bf16x8*)(lds + aoff[m] + ((kc ^ as7[m]) << 3));
#pragma unroll
      for (int n = 0; n < NR; ++n)
        bfr[kq][n] = *(const bf16x8*)(lds + boff[n] + ((kc ^ bs7[n]) << 3));
    }
#pragma unroll
    for (int kq = 0; kq < 2; ++kq)
#pragma unroll
      for (int m = 0; m < 4; ++m)
#pragma unroll
        for (int n = 0; n < NR; ++n)
          acc[m][n] = __builtin_amdgcn_mfma_f32_16x16x32_bf16(af[kq][m], bfr[kq][n],
                                                              acc[m][n], 0, 0, 0);
    __syncthreads();
  }

  // C/D layout: col = lane&15, row = (lane>>4)*4 + j
#pragma unroll
  for (int m = 0; m < 4; ++m) {
    const int rbase = row0 + wrow * 64 + m * 16 + lg * 4;
#pragma unroll
    for (int j = 0; j < 4; ++j) {
      const int r = rbase + j;
      if (EPI == 2) {
        const float rs = rsqrtf(rssq[r] * (1.f / 256.f) + 1e-6f);
#pragma unroll
        for (int n = 0; n < NR; ++n) {
          const int c = col0 + wcol * (BN_T / WC) + n * 16 + lr;
          ((u16*)Cv)[(long)r * N + c] = f2bf(acc[m][n][j] * rs);
        }
      } else if (EPI == 1 || EPI == 3) {
        float ssq = 0.f;
#pragma unroll
        for (int n = 0; n < NR; ++n) {
          const int c = col0 + wcol * (BN_T / WC) + n * 16 + lr;
          float v = acc[m][n][j] + (BIAS ? bias[c] : 0.f);
          const long off = (long)r * N + c;
          if (RES) v += bf2f(((u16*)Cv)[off]);
          ((u16*)Cv)[off] = f2bf(v);
          if (EPI == 1) ssq = fmaf(v, v, ssq);
        }
        if (EPI == 1) {
          ssq += __shfl_xor(ssq, 1); ssq += __shfl_xor(ssq, 2);
          ssq += __shfl_xor(ssq, 4); ssq += __shfl_xor(ssq, 8);
          if (lr == 0) atomicAdd(rssq + r, ssq);
        }
      } else {
#pragma unroll
        for (int n = 0; n < NR; ++n) {
          const int c = col0 + wcol * (BN_T / WC) + n * 16 + lr;
          if (NCHK && c >= N) continue;
          float v = acc[m][n][j] + (BIAS ? bias[c] : 0.f);
          float* p = (float*)Cv + (long)r * N + c;
          if (RES) *p += v; else *p = v;
        }
      }
    }
  }
}

// one-shot conversion of x + all weights to bf16; norm_w folded into in_w.
// Also zeroes pooled+rowssq (first 4352 float4s at zb).
__global__ __launch_bounds__(256) void megacvt_k(
    const float* __restrict__ x, const float* __restrict__ ew,
    const float* __restrict__ iw, const float* __restrict__ ow,
    const float* __restrict__ xw, const float* __restrict__ nw,
    u16* __restrict__ xb, u16* __restrict__ ewb, u16* __restrict__ iwb,
    u16* __restrict__ owb, u16* __restrict__ xwb, float* __restrict__ zb) {
  int i = blockIdx.x * 256 + threadIdx.x;
  if (i < 4352) ((float4*)zb)[i] = make_float4(0.f, 0.f, 0.f, 0.f);
  float4 v;
  u16* d; int di;
  if (i < 262144) { v = ((const float4*)x)[i]; d = xb; di = i; }
  else if ((i -= 262144) < 8192) { v = ((const float4*)ew)[i]; d = ewb; di = i; }
  else if ((i -= 8192) < 131072) {
    v = ((const float4*)iw)[i];
    const int layer = i >> 16;
    const float4 g = *(const float4*)(nw + layer * NDM + ((i & 63) << 2));
    v.x *= g.x; v.y *= g.y; v.z *= g.z; v.w *= g.w;
    d = iwb; di = i;
  }
  else if ((i -= 131072) < 65536) { v = ((const float4*)ow)[i]; d = owb; di = i; }
  else { i -= 65536; v = ((const float4*)xw)[i]; d = xwb; di = i; }
  ushort4 o;
  o.x = f2bf(v.x); o.y = f2bf(v.y); o.z = f2bf(v.z); o.w = f2bf(v.w);
  ((ushort4*)d)[di] = o;
}

// u2 = silu(depthwise causal conv(u)); bf16 in/out; 4 t-rows per block
__global__ __launch_bounds__(256) void conv_silu_k(const u16* __restrict__ xzb,
                                                   const float* __restrict__ cw,
                                                   const float* __restrict__ cb,
                                                   u16* __restrict__ u2b) {
  const int t0 = blockIdx.x * 4;
  const int l0 = t0 & (LSEQ - 1);
#pragma unroll
  for (int half = 0; half < 2; ++half) {
    const int ch = threadIdx.x + half * 256;
    const float w0 = cw[ch * 4], w1 = cw[ch * 4 + 1];
    const float w2 = cw[ch * 4 + 2], w3 = cw[ch * 4 + 3];
    const float bias = cb[ch];
    float v[7];
#pragma unroll
    for (int m = 0; m < 7; ++m) {
      const int tt = t0 - 3 + m;
      v[m] = (tt >= 0) ? bf2f(xzb[(long)tt * 1024 + ch]) : 0.f;
    }
#pragma unroll
    for (int j = 0; j < 4; ++j) {
      const int l = l0 + j;
      float acc = bias;
      if (l >= 3) acc = fmaf(v[j + 0], w0, acc);
      if (l >= 2) acc = fmaf(v[j + 1], w1, acc);
      if (l >= 1) acc = fmaf(v[j + 2], w2, acc);
      acc = fmaf(v[j + 3], w3, acc);
      u2b[(long)(t0 + j) * NDI + ch] = f2bf(acc * sigmoidf_(acc));
    }
  }
}

// ---- FUSED cooperative scan: phases A/B/C in one kernel, grid.sync between.
// Ac[16], dl[16], ul[16] stay live in registers across the barriers, so phase
// C skips the dbc re-read + dt-dot + softplus + u2 re-read entirely.
__global__ __launch_bounds__(256, 4) void scan_fused(
    const u16* __restrict__ u2b, const float* __restrict__ dbc,
    const u16* __restrict__ xzb, const float* __restrict__ dtw,
    const float* __restrict__ dtbv, const float* __restrict__ Alog,
    const float* __restrict__ Dp, u16* __restrict__ sEnd,
    float* __restrict__ daccv, u16* __restrict__ y) {
  const int d = ((blockIdx.x & 1) << 8) + threadIdx.x;
  const int cbk = blockIdx.x >> 1;
  const int c = cbk & (NCH - 1), b = cbk >> NCH_LOG;
  const int tbase = b * LSEQ + c * CHUNK;
  const long base = ((long)((b * NCH + c) * NDI + d)) * NDS;

  float Ac[16], dl[CHUNK], ul[CHUNK];
  // ---- phase A ----
  {
    float dtr[16];
#pragma unroll
    for (int q = 0; q < 4; ++q) {
      float4 v = *(const float4*)(Alog + d * NDS + q * 4);
      Ac[q * 4 + 0] = -__expf(v.x); Ac[q * 4 + 1] = -__expf(v.y);
      Ac[q * 4 + 2] = -__expf(v.z); Ac[q * 4 + 3] = -__expf(v.w);
      float4 w = *(const float4*)(dtw + d * NDR + q * 4);
      dtr[q * 4 + 0] = w.x; dtr[q * 4 + 1] = w.y;
      dtr[q * 4 + 2] = w.z; dtr[q * 4 + 3] = w.w;
    }
    const float dtb_d = dtbv[d];
#pragma unroll
    for (int j = 0; j < CHUNK; ++j) {
      const float* row = dbc + (long)(tbase + j) * 48;
      const float4 d0 = *(const float4*)(row);
      const float4 d1 = *(const float4*)(row + 4);
      const float4 d2 = *(const float4*)(row + 8);
      const float4 d3 = *(const float4*)(row + 12);
      const float p0 = fmaf(d0.x, dtr[0], fmaf(d1.x, dtr[4], fmaf(d2.x, dtr[8],  d3.x * dtr[12])));
      const float p1 = fmaf(d0.y, dtr[1], fmaf(d1.y, dtr[5], fmaf(d2.y, dtr[9],  d3.y * dtr[13])));
      const float p2 = fmaf(d0.z, dtr[2], fmaf(d1.z, dtr[6], fmaf(d2.z, dtr[10], d3.z * dtr[14])));
      const float p3 = fmaf(d0.w, dtr[3], fmaf(d1.w, dtr[7], fmaf(d2.w, dtr[11], d3.w * dtr[15])));
      dl[j] = softplus_(dtb_d + ((p0 + p1) + (p2 + p3)));
      ul[j] = bf2f(u2b[(long)(tbase + j) * NDI + d]);
    }
    float dacc = 0.f;
#pragma unroll
    for (int j = 0; j < CHUNK; ++j) dacc += dl[j];

    float s[16] = {};
#pragma unroll
    for (int j = 0; j < CHUNK; ++j) {
      const float* row = dbc + (long)(tbase + j) * 48 + NDR;
      const float dlj = dl[j], duj = dl[j] * ul[j];
#pragma unroll
      for (int q = 0; q < 4; ++q) {
        const float4 Bv = *(const float4*)(row + q * 4);
        const float Be[4] = {Bv.x, Bv.y, Bv.z, Bv.w};
#pragma unroll
        for (int e = 0; e < 4; ++e) {
          const int n = q * 4 + e;
          s[n] = fmaf(__expf(dlj * Ac[n]), s[n], duj * Be[e]);
        }
      }
    }
#pragma unroll
    for (int q = 0; q < 4; ++q) {
      ushort4 sv;
      sv.x = f2bf(s[q * 4 + 0]); sv.y = f2bf(s[q * 4 + 1]);
      sv.z = f2bf(s[q * 4 + 2]); sv.w = f2bf(s[q * 4 + 3]);
      *(ushort4*)(sEnd + base + q * 4) = sv;
    }
    daccv[(b * NCH + c) * NDI + d] = dacc;
  }

  cg::this_grid().sync();

  // ---- phase B (first 32768 threads): sEnd -> carry, in place ----
  {
    const int g = blockIdx.x * 256 + threadIdx.x;
    if (g < BATCH * NDI * NDS) {
      const int dn = g & (NDI * NDS - 1);
      const int bb = g >> 13;
      const int dd = dn >> 4, nn = dn & 15;
      const float Acn = -__expf(Alog[dd * NDS + nn]);
      float h = 0.f;
      const long bbase = (long)bb * NCH * NDI * NDS + dn;
      const int dbase = bb * NCH * NDI + dd;
      for (int c0 = 0; c0 < NCH; c0 += 32) {
        u16 pe[32]; float da[32];
#pragma unroll
        for (int j = 0; j < 32; ++j) {
          pe[j] = sEnd[bbase + (long)(c0 + j) * (NDI * NDS)];
          da[j] = daccv[dbase + (c0 + j) * NDI];
        }
#pragma unroll
        for (int j = 0; j < 32; ++j) {
          sEnd[bbase + (long)(c0 + j) * (NDI * NDS)] = f2bf(h);
          h = fmaf(__expf(Acn * da[j]), h, bf2f(pe[j]));
        }
      }
    }
  }

  cg::this_grid().sync();

  // ---- phase C: recurrence from carry, C-contraction, u*D, silu(z) gate ----
  {
    const float Dv = Dp[d];
    float s[16];
    const bf16x8 c0v = *(const bf16x8*)(sEnd + base);
    const bf16x8 c1v = *(const bf16x8*)(sEnd + base + 8);
#pragma unroll
    for (int n = 0; n < 8; ++n) {
      s[n] = bf2f((u16)c0v[n]);
      s[8 + n] = bf2f((u16)c1v[n]);
    }
#pragma unroll
    for (int j = 0; j < CHUNK; ++j) {
      const int t = tbase + j;
      const float* row = dbc + (long)t * 48 + NDR;
      const float dlj = dl[j];
      const float duj = dlj * ul[j];
      float pp[4];
#pragma unroll
      for (int q = 0; q < 4; ++q) {
        const float4 Bv = *(const float4*)(row + q * 4);
        const float4 Cq = *(const float4*)(row + NDS + q * 4);
        const float Be[4] = {Bv.x, Bv.y, Bv.z, Bv.w};
        const float Ce[4] = {Cq.x, Cq.y, Cq.z, Cq.w};
        float p = 0.f;
#pragma unroll
        for (int e = 0; e < 4; ++e) {
          const int n = q * 4 + e;
          s[n] = fmaf(__expf(dlj * Ac[n]), s[n], duj * Be[e]);
          p = fmaf(s[n], Ce[e], p);
        }
        pp[q] = p;
      }
      const float p = (pp[0] + pp[1]) + (pp[2] + pp[3]);
      const float zl = bf2f(xzb[(long)t * 1024 + NDI + d]);
      y[(long)t * NDI + d] = f2bf((p + ul[j] * Dv) * zl * sigmoidf_(zl));
    }
  }
}

// ---- fallback 3-kernel scan path (identical math) ----
__global__ __launch_bounds__(256) void scanA(const u16* __restrict__ u2b,
                                             const float* __restrict__ dbc,
                                             const float* __restrict__ dtw,
                                             const float* __restrict__ dtbv,
                                             const float* __restrict__ Alog,
                                             u16* __restrict__ sEnd,
                                             float* __restrict__ daccv) {
  const int d = ((blockIdx.x & 1) << 8) + threadIdx.x;
  const int cb = blockIdx.x >> 1;
  const int c = cb & (NCH - 1), b = cb >> NCH_LOG;
  float Ac[16], dtr[16];
#pragma unroll
  for (int q = 0; q < 4; ++q) {
    float4 v = *(const float4*)(Alog + d * NDS + q * 4);
    Ac[q * 4 + 0] = -__expf(v.x); Ac[q * 4 + 1] = -__expf(v.y);
    Ac[q * 4 + 2] = -__expf(v.z); Ac[q * 4 + 3] = -__expf(v.w);
    float4 w = *(const float4*)(dtw + d * NDR + q * 4);
    dtr[q * 4 + 0] = w.x; dtr[q * 4 + 1] = w.y; dtr[q * 4 + 2] = w.z; dtr[q * 4 + 3] = w.w;
  }
  const float dtb_d = dtbv[d];
  const int tbase = b * LSEQ + c * CHUNK;
  float dl[CHUNK], du[CHUNK];
#pragma unroll
  for (int j = 0; j < CHUNK; ++j) {
    const float* row = dbc + (long)(tbase + j) * 48;
    const float4 d0 = *(const float4*)(row);
    const float4 d1 = *(const float4*)(row + 4);
    const float4 d2 = *(const float4*)(row + 8);
    const float4 d3 = *(const float4*)(row + 12);
    const float p0 = fmaf(d0.x, dtr[0], fmaf(d1.x, dtr[4], fmaf(d2.x, dtr[8],  d3.x * dtr[12])));
    const float p1 = fmaf(d0.y, dtr[1], fmaf(d1.y, dtr[5], fmaf(d2.y, dtr[9],  d3.y * dtr[13])));
    const float p2 = fmaf(d0.z, dtr[2], fmaf(d1.z, dtr[6], fmaf(d2.z, dtr[10], d3.z * dtr[14])));
    const float p3 = fmaf(d0.w, dtr[3], fmaf(d1.w, dtr[7], fmaf(d2.w, dtr[11], d3.w * dtr[15])));
    dl[j] = softplus_(dtb_d + ((p0 + p1) + (p2 + p3)));
    du[j] = dl[j] * bf2f(u2b[(long)(tbase + j) * NDI + d]);
  }
  float dacc = 0.f;
#pragma unroll
  for (int j = 0; j < CHUNK; ++j) dacc += dl[j];
  float s[16] = {};
#pragma unroll
  for (int j = 0; j < CHUNK; ++j) {
    const float* row = dbc + (long)(tbase + j) * 48 + NDR;
    const float dlj = dl[j], duj = du[j];
#pragma unroll
    for (int q = 0; q < 4; ++q) {
      const float4 Bv = *(const float4*)(row + q * 4);
      const float Be[4] = {Bv.x, Bv.y, Bv.z, Bv.w};
#pragma unroll
      for (int e = 0; e < 4; ++e) {
        const int n = q * 4 + e;
        s[n] = fmaf(__expf(dlj * Ac[n]), s[n], duj * Be[e]);
      }
    }
  }
  const long base = ((long)((b * NCH + c) * NDI + d)) * NDS;
#pragma unroll
  for (int q = 0; q < 4; ++q) {
    ushort4 sv;
    sv.x = f2bf(s[q * 4 + 0]); sv.y = f2bf(s[q * 4 + 1]);
    sv.z = f2bf(s[q * 4 + 2]); sv.w = f2bf(s[q * 4 + 3]);
    *(ushort4*)(sEnd + base + q * 4) = sv;
  }
  daccv[(b * NCH + c) * NDI + d] = dacc;
}

__global__ __launch_bounds__(256) void scanB(u16* __restrict__ sp,
                                             const float* __restrict__ daccv,
                                             const float* __restrict__ Alog) {
  const int g = blockIdx.x * 256 + threadIdx.x;
  const int dn = g & (NDI * NDS - 1);
  const int b = g >> 13;
  const int d = dn >> 4, n = dn & 15;
  const float Acn = -__expf(Alog[d * NDS + n]);
  float h = 0.f;
  const long base = (long)b * NCH * NDI * NDS + dn;
  const int dbase = b * NCH * NDI + d;
  for (int c0 = 0; c0 < NCH; c0 += 32) {
    u16 pe[32]; float da[32];
#pragma unroll
    for (int j = 0; j < 32; ++j) {
      pe[j] = sp[base + (long)(c0 + j) * (NDI * NDS)];
      da[j] = daccv[dbase + (c0 + j) * NDI];
    }
#pragma unroll
    for (int j = 0; j < 32; ++j) {
      sp[base + (long)(c0 + j) * (NDI * NDS)] = f2bf(h);
      h = fmaf(__expf(Acn * da[j]), h, bf2f(pe[j]));
    }
  }
}

__global__ __launch_bounds__(256) void scanC(const u16* __restrict__ u2b,
                                             const float* __restrict__ dbc,
                                             const u16* __restrict__ xzb,
                                             const float* __restrict__ dtw,
                                             const float* __restrict__ dtbv,
                                             const float* __restrict__ Alog,
                                             const float* __restrict__ Dp,
                                             const u16* __restrict__ carry,
                                             u16* __restrict__ y) {
  const int d = ((blockIdx.x & 1) << 8) + threadIdx.x;
  const int cb = blockIdx.x >> 1;
  const int c = cb & (NCH - 1), b = cb >> NCH_LOG;
  float Ac[16], dtr[16];
#pragma unroll
  for (int q = 0; q < 4; ++q) {
    float4 v = *(const float4*)(Alog + d * NDS + q * 4);
    Ac[q * 4 + 0] = -__expf(v.x); Ac[q * 4 + 1] = -__expf(v.y);
    Ac[q * 4 + 2] = -__expf(v.z); Ac[q * 4 + 3] = -__expf(v.w);
    float4 w = *(const float4*)(dtw + d * NDR + q * 4);
    dtr[q * 4 + 0] = w.x; dtr[q * 4 + 1] = w.y; dtr[q * 4 + 2] = w.z; dtr[q * 4 + 3] = w.w;
  }
  const float dtb_d = dtbv[d];
  const float Dv = Dp[d];
  const int tbase = b * LSEQ + c * CHUNK;
  float dl[CHUNK], ul[CHUNK];
#pragma unroll
  for (int j = 0; j < CHUNK; ++j) {
    const float* row = dbc + (long)(tbase + j) * 48;
    const float4 d0 = *(const float4*)(row);
    const float4 d1 = *(const float4*)(row + 4);
    const float4 d2 = *(const float4*)(row + 8);
    const float4 d3 = *(const float4*)(row + 12);
    const float p0 = fmaf(d0.x, dtr[0], fmaf(d1.x, dtr[4], fmaf(d2.x, dtr[8],  d3.x * dtr[12])));
    const float p1 = fmaf(d0.y, dtr[1], fmaf(d1.y, dtr[5], fmaf(d2.y, dtr[9],  d3.y * dtr[13])));
    const float p2 = fmaf(d0.z, dtr[2], fmaf(d1.z, dtr[6], fmaf(d2.z, dtr[10], d3.z * dtr[14])));
    const float p3 = fmaf(d0.w, dtr[3], fmaf(d1.w, dtr[7], fmaf(d2.w, dtr[11], d3.w * dtr[15])));
    dl[j] = softplus_(dtb_d + ((p0 + p1) + (p2 + p3)));
    ul[j] = bf2f(u2b[(long)(tbase + j) * NDI + d]);
  }
  float s[16];
  const long base = ((long)((b * NCH + c) * NDI + d)) * NDS;
  {
    const bf16x8 c0v = *(const bf16x8*)(carry + base);
    const bf16x8 c1v = *(const bf16x8*)(carry + base + 8);
#pragma unroll
    for (int n = 0; n < 8; ++n) {
      s[n] = bf2f((u16)c0v[n]);
      s[8 + n] = bf2f((u16)c1v[n]);
    }
  }
#pragma unroll
  for (int j = 0; j < CHUNK; ++j) {
    const int t = tbase + j;
    const float* row = dbc + (long)t * 48 + NDR;
    const float dlj = dl[j];
    const float duj = dlj * ul[j];
    float pp[4];
#pragma unroll
    for (int q = 0; q < 4; ++q) {
      const float4 Bv = *(const float4*)(row + q * 4);
      const float4 Cq = *(const float4*)(row + NDS + q * 4);
      const float Be[4] = {Bv.x, Bv.y, Bv.z, Bv.w};
      const float Ce[4] = {Cq.x, Cq.y, Cq.z, Cq.w};
      float p = 0.f;
#pragma unroll
      for (int e = 0; e < 4; ++e) {
        const int n = q * 4 + e;
        s[n] = fmaf(__expf(dlj * Ac[n]), s[n], duj * Be[e]);
        p = fmaf(s[n], Ce[e], p);
      }
      pp[q] = p;
    }
    const float p = (pp[0] + pp[1]) + (pp[2] + pp[3]);
    const float zl = bf2f(xzb[(long)t * 1024 + NDI + d]);
    y[(long)t * NDI + d] = f2bf((p + ul[j] * Dv) * zl * sigmoidf_(zl));
  }
}

// fused final rmsnorm + mean-pool on bf16 h: block = 32 rows, wave per row
__global__ __launch_bounds__(256) void finalpool_k(const u16* __restrict__ hb,
                                                   const float* __restrict__ w,
                                                   float* __restrict__ pooled) {
  const int wave = threadIdx.x >> 6, lane = threadIdx.x & 63;
  const int t0 = blockIdx.x * 32;
  const int b = t0 >> 11;
  const float4 wv = ((const float4*)w)[lane];
  float a0 = 0.f, a1 = 0.f, a2 = 0.f, a3 = 0.f;
  for (int r = wave; r < 32; r += 4) {
    const ushort4 hv = ((const ushort4*)(hb + (long)(t0 + r) * NDM))[lane];
    const float vx = bf2f(hv.x), vy = bf2f(hv.y), vz = bf2f(hv.z), vw = bf2f(hv.w);
    float ss = vx * vx + vy * vy + vz * vz + vw * vw;
#pragma unroll
    for (int off = 32; off >= 1; off >>= 1) ss += __shfl_xor(ss, off);
    const float rs = rsqrtf(ss * (1.f / NDM) + 1e-6f);
    a0 = fmaf(vx * rs, wv.x, a0); a1 = fmaf(vy * rs, wv.y, a1);
    a2 = fmaf(vz * rs, wv.z, a2); a3 = fmaf(vw * rs, wv.w, a3);
  }
  __shared__ float red[4][NDM];
  red[wave][lane * 4 + 0] = a0; red[wave][lane * 4 + 1] = a1;
  red[wave][lane * 4 + 2] = a2; red[wave][lane * 4 + 3] = a3;
  __syncthreads();
  if (wave == 0) {
#pragma unroll
    for (int e = 0; e < 4; ++e) {
      const int dc = lane * 4 + e;
      const float sum = red[0][dc] + red[1][dc] + red[2][dc] + red[3][dc];
      atomicAdd(pooled + b * NDM + dc, sum * (1.f / LSEQ));
    }
  }
}

// wave per (b,f): lane-parallel 256-len dot + shuffle reduce (128 blocks)
__global__ __launch_bounds__(256) void bias_k(const float* __restrict__ pooled,
                                              const float* __restrict__ pw,
                                              const float* __restrict__ pb,
                                              float* __restrict__ bv) {
  const int w = blockIdx.x * 4 + (threadIdx.x >> 6);
  const int lane = threadIdx.x & 63;
  const int b = w >> 7, f = w & 127;
  const float4 pv = ((const float4*)(pooled + b * NDM))[lane];
  const float4 wv = ((const float4*)(pw + f * NDM))[lane];
  float acc = pv.x * wv.x + pv.y * wv.y + pv.z * wv.z + pv.w * wv.w;
#pragma unroll
  for (int off = 32; off >= 1; off >>= 1) acc += __shfl_xor(acc, off);
  if (lane == 0) bv[b * NF + f] = acc + pb[f];
}

__global__ __launch_bounds__(256) void addout_k(const float* __restrict__ x,
                                                const float* __restrict__ bv,
                                                float* __restrict__ out) {
  const int i4 = blockIdx.x * 256 + threadIdx.x;
  const float4 xv = ((const float4*)x)[i4];
  const int trow = i4 >> 5;
  const int b = trow >> 11;
  const int f4 = i4 & 31;
  const float4 bb = ((const float4*)bv)[b * 32 + f4];
  float4 o;
  o.x = xv.x + bb.x; o.y = xv.y + bb.y; o.z = xv.z + bb.z; o.w = xv.w + bb.w;
  ((float4*)out)[i4] = o;
}

extern "C" void kernel_launch(void* const* d_in, const int* in_sizes, int n_in,
                              void* d_out, int out_size, void* d_ws, size_t ws_size,
                              hipStream_t stream) {
  const float* x       = (const float*)d_in[0];
  const float* embed_w = (const float*)d_in[1];
  const float* embed_b = (const float*)d_in[2];
  const float* in_w    = (const float*)d_in[3];
  const float* conv_w  = (const float*)d_in[4];
  const float* conv_b  = (const float*)d_in[5];
  const float* xproj_w = (const float*)d_in[6];
  const float* dt_w    = (const float*)d_in[7];
  const float* dt_b    = (const float*)d_in[8];
  const float* A_log   = (const float*)d_in[9];
  const float* Dw      = (const float*)d_in[10];
  const float* out_w   = (const float*)d_in[11];
  const float* norm_w  = (const float*)d_in[12];
  const float* fnorm_w = (const float*)d_in[13];
  const float* proj_w  = (const float*)d_in[14];
  const float* proj_b  = (const float*)d_in[15];

  // workspace layout (f32 units), ~53 MB (ws = 268 MB). Full audit (R4 rule):
  float* ws      = (float*)d_ws;
  float* hbr     = ws;                     // 1,048,576 f32-eq: hb bf16 (2,097,152)
  float* xzr     = hbr  + 1048576;         // 4,194,304 f32-eq: xzb bf16 (8,388,608)
  float* u2r     = xzr  + 4194304;         // 2,097,152 f32-eq: u2b bf16 (4,194,304)
  float* ybr     = u2r  + 2097152;         // 2,097,152 f32-eq: ybb bf16 (4,194,304)
  float* dbc     = ybr  + 2097152;         // 393,216 f32
  float* sEndr   = dbc  + 393216;          // 2,097,152 f32-eq: sEnd bf16 (4,194,304)
  float* daccv   = sEndr + 2097152;        // 262,144 f32 (BATCH*NCH*NDI exactly)
  float* xbr     = daccv + 262144;         // 524,288 f32-eq: xb bf16 (1,048,576)
  float* inwr    = xbr  + 524288;          // 262,144 f32-eq: in_w' bf16
  float* owr     = inwr + 262144;          // 131,072 f32-eq: out_w bf16
  float* xpwr    = owr  + 131072;          // 24,576 f32-eq: xproj_w bf16
  float* ewr     = xpwr + 24576;           // 16,384 f32-eq: embed_w bf16
  float* pooled  = ewr  + 16384;           // 1,024   --+ zeroed by megacvt
  float* rowssq0 = pooled + 1024;          // 8,192     | (17,408 f32 = 4,352 f4)
  float* rowssq1 = rowssq0 + 8192;         // 8,192   --+
  float* bv      = rowssq1 + 8192;         // 512

  u16* ybb  = (u16*)ybr;
  u16* hb   = (u16*)hbr;
  u16* xzb  = (u16*)xzr;
  u16* u2b  = (u16*)u2r;
  u16* sEnd = (u16*)sEndr;
  u16* xb   = (u16*)xbr;
  u16* inwb = (u16*)inwr;
  u16* owb  = (u16*)owr;
  u16* xpwb = (u16*)xpwr;
  u16* ewb  = (u16*)ewr;

  megacvt_k<<<1872, 256, 0, stream>>>(x, embed_w, in_w, out_w, xproj_w, norm_w,
                                      xb, ewb, inwb, owb, xpwb, pooled);

  // hb = bf16(x @ embed_w^T + embed_b)  (EPI=1 -> hb + rowssq0)
  gemm_bf16<128, 64, true, false, false, 1><<<dim3(4, 64), 256, 0, stream>>>(
      xb, ewb, embed_b, hb, NDM, NF, rowssq0);

  for (int i = 0; i < 2; ++i) {
    const float* cw  = conv_w + (long)i * NDI * 4;
    const float* cb  = conv_b + (long)i * NDI;
    const float* dtw = dt_w   + (long)i * NDI * NDR;
    const float* dtb = dt_b   + (long)i * NDI;
    const float* al  = A_log  + (long)i * NDI * NDS;
    const float* dd  = Dw     + (long)i * NDI;
    float* rsq       = i ? rowssq1 : rowssq0;

    // xz = rmsnorm(h) @ in_w'^T  (commuted RMS epilogue)
    gemm_bf16<128, 128, false, false, false, 2><<<dim3(8, 64), 256, 0, stream>>>(
        hb, inwb + (long)i * 2 * NDI * NDM, nullptr, xzb, 1024, NDM, rsq);
    conv_silu_k<<<TTOK / 4, 256, 0, stream>>>(xzb, cw, cb, u2b);
    // dbc = u2 @ xproj_w^T  (MFMA, 128 blocks, N=48 clamped)
    gemm_bf16<64, 64, false, false, true, 0><<<dim3(1, 128), 256, 0, stream>>>(
        u2b, xpwb + (long)i * 48 * NDI, nullptr, dbc, 48, NDI, nullptr);

    // fused cooperative scan (A+B+C, regs live across grid syncs);
    // fallback to 3-kernel path if cooperative launch is rejected.
    void* cargs[] = {(void*)&u2b, (void*)&dbc, (void*)&xzb, (void*)&dtw,
                     (void*)&dtb, (void*)&al, (void*)&dd, (void*)&sEnd,
                     (void*)&daccv, (void*)&ybb};
    hipError_t cerr = hipLaunchCooperativeKernel(
        (const void*)scan_fused, dim3(BATCH * NCH * 2), dim3(256), cargs, 0, stream);
    if (cerr != hipSuccess) {
      scanA<<<BATCH * NCH * 2, 256, 0, stream>>>(u2b, dbc, dtw, dtb, al, sEnd, daccv);
      scanB<<<BATCH * NDI * NDS / 256, 256, 0, stream>>>(sEnd, daccv, al);
      scanC<<<BATCH * NCH * 2, 256, 0, stream>>>(u2b, dbc, xzb, dtw, dtb, al, dd,
                                                 sEnd, ybb);
    }

    // h += yb @ out_w^T (bf16 residual); L0 also emits rowssq1 (EPI=1)
    if (i == 0)
      gemm_bf16<128, 64, false, true, false, 1><<<dim3(4, 64), 256, 0, stream>>>(
          ybb, owb, nullptr, hb, NDM, NDI, rowssq1);
    else
      gemm_bf16<128, 64, false, true, false, 3><<<dim3(4, 64), 256, 0, stream>>>(
          ybb, owb + (long)NDM * NDI, nullptr, hb, NDM, NDI, nullptr);
  }

  finalpool_k<<<TTOK / 32, 256, 0, stream>>>(hb, fnorm_w, pooled);
  bias_k<<<128, 256, 0, stream>>>(pooled, proj_w, proj_b, bv);
  addout_k<<<TTOK * NF / 4 / 256, 256, 0, stream>>>(x, bv, (float*)d_out);
}

// Round 13
// 272.899 us; speedup vs baseline: 3.9894x; 3.9894x over previous
//
#include <hip/hip_runtime.h>

#define TTOK 8192   // B*L
#define BATCH 4
#define LSEQ 2048
#define NDM 256
#define NF 128
#define NDI 512
#define NDS 16
#define NDR 16
#define CHUNK 16
#define NCH (LSEQ / CHUNK)   // 128
#define NCH_LOG 7

typedef unsigned short u16;
typedef __attribute__((ext_vector_type(8))) short bf16x8;
typedef __attribute__((ext_vector_type(4))) float f32x4;

__device__ __forceinline__ float sigmoidf_(float x) { return 1.f / (1.f + __expf(-x)); }

__device__ __forceinline__ u16 f2bf(float f) {  // RTN-even
  unsigned u = __float_as_uint(f);
  u += 0x7FFF + ((u >> 16) & 1);
  return (u16)(u >> 16);
}
__device__ __forceinline__ float bf2f(u16 v) {
  return __uint_as_float((unsigned)v << 16);
}
__device__ __forceinline__ float softplus_(float x) {  // stable
  return fmaxf(x, 0.f) + __logf(1.f + __expf(-fabsf(x)));
}

// ---------------- bf16 MFMA GEMM ----------------
// C = A·W^T (+bias) (+= if RES). A:[M][K] bf16, W:[N][K] bf16.
// Tile BM_T x BN_T, BK=64, 4 waves. NCHK: clamp W rows / skip cols >= N.
// EPI: 0 = f32 out. 1 = bf16 out (+bf16 residual if RES) + per-row ssq
//      atomicAdd into rssq. 2 = "RMS": scale by rsqrt(rssq[r]/256+eps), bf16
//      out. 3 = bf16 out (+bf16 residual), plain.
// R11 lesson (permanent): do NOT fuse the scan phases with cooperative
// grid.sync — each grid-wide sync on 8-XCD MI355X forces a cross-XCD L2
// flush (~630 MB traffic, ~450 us). Kernel boundaries are the cheap sync.
template<int BM_T, int BN_T, bool BIAS, bool RES, bool NCHK, int EPI>
__global__ __launch_bounds__(256) void gemm_bf16(const u16* __restrict__ A,
                                                 const u16* __restrict__ W,
                                                 const float* __restrict__ bias,
                                                 void* __restrict__ Cv,
                                                 int N, int K,
                                                 float* __restrict__ rssq) {
  constexpr int WR = BM_T / 64;
  constexpr int WC = 4 / WR;
  constexpr int NR = BN_T / (16 * WC);
  constexpr int ROWS = BM_T + BN_T;
  constexpr int CPW = ROWS / 32;
  __shared__ u16 lds[ROWS * 64];
  const int tid = threadIdx.x;
  const int wave = tid >> 6, lane = tid & 63;
  const int wrow = wave / WC, wcol = wave % WC;
  const int lr = lane & 15, lg = lane >> 4;
  const int row0 = blockIdx.y * BM_T, col0 = blockIdx.x * BN_T;

  const u16* srcp[CPW];
  u16* ldsp[CPW];
#pragma unroll
  for (int i = 0; i < CPW; ++i) {
    const int q = wave * CPW + i;
    const int row = q * 8 + (lane >> 3);
    const int ck = lane & 7;
    const int sck = ck ^ (row & 7);
    long grow;
    if (row < BM_T) grow = (long)(row0 + row) * K;
    else {
      int wr = row - BM_T;
      if (NCHK && wr >= N) wr = N - 1;
      grow = (long)(col0 + wr) * K;
    }
    srcp[i] = ((row < BM_T) ? A : W) + grow + sck * 8;
    ldsp[i] = (u16*)&lds[q * 512];
  }

  int aoff[4], as7[4], boff[NR], bs7[NR];
#pragma unroll
  for (int m = 0; m < 4; ++m) {
    const int r = wrow * 64 + m * 16 + lr;
    aoff[m] = r * 64; as7[m] = r & 7;
  }
#pragma unroll
  for (int n = 0; n < NR; ++n) {
    const int r = BM_T + wcol * (BN_T / WC) + n * 16 + lr;
    boff[n] = r * 64; bs7[n] = r & 7;
  }

  f32x4 acc[4][NR];
#pragma unroll
  for (int m = 0; m < 4; ++m)
#pragma unroll
    for (int n = 0; n < NR; ++n) acc[m][n] = (f32x4)(0.f);

  for (int k0 = 0; k0 < K; k0 += 64) {
#pragma unroll
    for (int i = 0; i < CPW; ++i)
      __builtin_amdgcn_global_load_lds(
          (const __attribute__((address_space(1))) unsigned int*)(srcp[i] + k0),
          (__attribute__((address_space(3))) unsigned int*)(ldsp[i]), 16, 0, 0);
    __syncthreads();

    bf16x8 af[2][4], bfr[2][NR];
#pragma unroll
    for (int kq = 0; kq < 2; ++kq) {
      const int kc = kq * 4 + lg;
#pragma unroll
      for (int m = 0; m < 4; ++m)
        af[kq][m] = *(const bf16x8*)(lds + aoff[m] + ((kc ^ as7[m]) << 3));
#pragma unroll
      for (int n = 0; n < NR; ++n)
        bfr[kq][n] = *(const bf16x8*)(lds + boff[n] + ((kc ^ bs7[n]) << 3));
    }
#pragma unroll
    for (int kq = 0; kq < 2; ++kq)
#pragma unroll
      for (int m = 0; m < 4; ++m)
#pragma unroll
        for (int n = 0; n < NR; ++n)
          acc[m][n] = __builtin_amdgcn_mfma_f32_16x16x32_bf16(af[kq][m], bfr[kq][n],
                                                              acc[m][n], 0, 0, 0);
    __syncthreads();
  }

  // C/D layout: col = lane&15, row = (lane>>4)*4 + j
#pragma unroll
  for (int m = 0; m < 4; ++m) {
    const int rbase = row0 + wrow * 64 + m * 16 + lg * 4;
#pragma unroll
    for (int j = 0; j < 4; ++j) {
      const int r = rbase + j;
      if (EPI == 2) {
        const float rs = rsqrtf(rssq[r] * (1.f / 256.f) + 1e-6f);
#pragma unroll
        for (int n = 0; n < NR; ++n) {
          const int c = col0 + wcol * (BN_T / WC) + n * 16 + lr;
          ((u16*)Cv)[(long)r * N + c] = f2bf(acc[m][n][j] * rs);
        }
      } else if (EPI == 1 || EPI == 3) {
        float ssq = 0.f;
#pragma unroll
        for (int n = 0; n < NR; ++n) {
          const int c = col0 + wcol * (BN_T / WC) + n * 16 + lr;
          float v = acc[m][n][j] + (BIAS ? bias[c] : 0.f);
          const long off = (long)r * N + c;
          if (RES) v += bf2f(((u16*)Cv)[off]);
          ((u16*)Cv)[off] = f2bf(v);
          if (EPI == 1) ssq = fmaf(v, v, ssq);
        }
        if (EPI == 1) {
          ssq += __shfl_xor(ssq, 1); ssq += __shfl_xor(ssq, 2);
          ssq += __shfl_xor(ssq, 4); ssq += __shfl_xor(ssq, 8);
          if (lr == 0) atomicAdd(rssq + r, ssq);
        }
      } else {
#pragma unroll
        for (int n = 0; n < NR; ++n) {
          const int c = col0 + wcol * (BN_T / WC) + n * 16 + lr;
          if (NCHK && c >= N) continue;
          float v = acc[m][n][j] + (BIAS ? bias[c] : 0.f);
          float* p = (float*)Cv + (long)r * N + c;
          if (RES) *p += v; else *p = v;
        }
      }
    }
  }
}

// one-shot conversion of x + all weights to bf16; norm_w folded into in_w.
// Also zeroes pooled+rowssq (first 4352 float4s at zb).
__global__ __launch_bounds__(256) void megacvt_k(
    const float* __restrict__ x, const float* __restrict__ ew,
    const float* __restrict__ iw, const float* __restrict__ ow,
    const float* __restrict__ xw, const float* __restrict__ nw,
    u16* __restrict__ xb, u16* __restrict__ ewb, u16* __restrict__ iwb,
    u16* __restrict__ owb, u16* __restrict__ xwb, float* __restrict__ zb) {
  int i = blockIdx.x * 256 + threadIdx.x;
  if (i < 4352) ((float4*)zb)[i] = make_float4(0.f, 0.f, 0.f, 0.f);
  float4 v;
  u16* d; int di;
  if (i < 262144) { v = ((const float4*)x)[i]; d = xb; di = i; }
  else if ((i -= 262144) < 8192) { v = ((const float4*)ew)[i]; d = ewb; di = i; }
  else if ((i -= 8192) < 131072) {
    v = ((const float4*)iw)[i];
    const int layer = i >> 16;
    const float4 g = *(const float4*)(nw + layer * NDM + ((i & 63) << 2));
    v.x *= g.x; v.y *= g.y; v.z *= g.z; v.w *= g.w;
    d = iwb; di = i;
  }
  else if ((i -= 131072) < 65536) { v = ((const float4*)ow)[i]; d = owb; di = i; }
  else { i -= 65536; v = ((const float4*)xw)[i]; d = xwb; di = i; }
  ushort4 o;
  o.x = f2bf(v.x); o.y = f2bf(v.y); o.z = f2bf(v.z); o.w = f2bf(v.w);
  ((ushort4*)d)[di] = o;
}

// u2 = silu(depthwise causal conv(u)); bf16 in/out; 4 t-rows per block
__global__ __launch_bounds__(256) void conv_silu_k(const u16* __restrict__ xzb,
                                                   const float* __restrict__ cw,
                                                   const float* __restrict__ cb,
                                                   u16* __restrict__ u2b) {
  const int t0 = blockIdx.x * 4;
  const int l0 = t0 & (LSEQ - 1);
#pragma unroll
  for (int half = 0; half < 2; ++half) {
    const int ch = threadIdx.x + half * 256;
    const float w0 = cw[ch * 4], w1 = cw[ch * 4 + 1];
    const float w2 = cw[ch * 4 + 2], w3 = cw[ch * 4 + 3];
    const float bias = cb[ch];
    float v[7];
#pragma unroll
    for (int m = 0; m < 7; ++m) {
      const int tt = t0 - 3 + m;
      v[m] = (tt >= 0) ? bf2f(xzb[(long)tt * 1024 + ch]) : 0.f;
    }
#pragma unroll
    for (int j = 0; j < 4; ++j) {
      const int l = l0 + j;
      float acc = bias;
      if (l >= 3) acc = fmaf(v[j + 0], w0, acc);
      if (l >= 2) acc = fmaf(v[j + 1], w1, acc);
      if (l >= 1) acc = fmaf(v[j + 2], w2, acc);
      acc = fmaf(v[j + 3], w3, acc);
      u2b[(long)(t0 + j) * NDI + ch] = f2bf(acc * sigmoidf_(acc));
    }
  }
}

// ---- chunked parallel scan, thread-per-(b,c,d), 16 states in regs.
// 3-kernel path (R11: cooperative fusion is 4x WORSE — grid.sync flushes L2).

__global__ __launch_bounds__(256) void scanA(const u16* __restrict__ u2b,
                                             const float* __restrict__ dbc,
                                             const float* __restrict__ dtw,
                                             const float* __restrict__ dtbv,
                                             const float* __restrict__ Alog,
                                             u16* __restrict__ sEnd,
                                             float* __restrict__ daccv) {
  const int d = ((blockIdx.x & 1) << 8) + threadIdx.x;
  const int cb = blockIdx.x >> 1;
  const int c = cb & (NCH - 1), b = cb >> NCH_LOG;
  float Ac[16], dtr[16];
#pragma unroll
  for (int q = 0; q < 4; ++q) {
    float4 v = *(const float4*)(Alog + d * NDS + q * 4);
    Ac[q * 4 + 0] = -__expf(v.x); Ac[q * 4 + 1] = -__expf(v.y);
    Ac[q * 4 + 2] = -__expf(v.z); Ac[q * 4 + 3] = -__expf(v.w);
    float4 w = *(const float4*)(dtw + d * NDR + q * 4);
    dtr[q * 4 + 0] = w.x; dtr[q * 4 + 1] = w.y; dtr[q * 4 + 2] = w.z; dtr[q * 4 + 3] = w.w;
  }
  const float dtb_d = dtbv[d];
  const int tbase = b * LSEQ + c * CHUNK;
  float dl[CHUNK], du[CHUNK];
#pragma unroll
  for (int j = 0; j < CHUNK; ++j) {
    const float* row = dbc + (long)(tbase + j) * 48;
    const float4 d0 = *(const float4*)(row);
    const float4 d1 = *(const float4*)(row + 4);
    const float4 d2 = *(const float4*)(row + 8);
    const float4 d3 = *(const float4*)(row + 12);
    const float p0 = fmaf(d0.x, dtr[0], fmaf(d1.x, dtr[4], fmaf(d2.x, dtr[8],  d3.x * dtr[12])));
    const float p1 = fmaf(d0.y, dtr[1], fmaf(d1.y, dtr[5], fmaf(d2.y, dtr[9],  d3.y * dtr[13])));
    const float p2 = fmaf(d0.z, dtr[2], fmaf(d1.z, dtr[6], fmaf(d2.z, dtr[10], d3.z * dtr[14])));
    const float p3 = fmaf(d0.w, dtr[3], fmaf(d1.w, dtr[7], fmaf(d2.w, dtr[11], d3.w * dtr[15])));
    dl[j] = softplus_(dtb_d + ((p0 + p1) + (p2 + p3)));
    du[j] = dl[j] * bf2f(u2b[(long)(tbase + j) * NDI + d]);
  }
  float dacc = 0.f;
#pragma unroll
  for (int j = 0; j < CHUNK; ++j) dacc += dl[j];
  float s[16] = {};
#pragma unroll
  for (int j = 0; j < CHUNK; ++j) {
    const float* row = dbc + (long)(tbase + j) * 48 + NDR;
    const float dlj = dl[j], duj = du[j];
#pragma unroll
    for (int q = 0; q < 4; ++q) {
      const float4 Bv = *(const float4*)(row + q * 4);
      const float Be[4] = {Bv.x, Bv.y, Bv.z, Bv.w};
#pragma unroll
      for (int e = 0; e < 4; ++e) {
        const int n = q * 4 + e;
        s[n] = fmaf(__expf(dlj * Ac[n]), s[n], duj * Be[e]);
      }
    }
  }
  const long base = ((long)((b * NCH + c) * NDI + d)) * NDS;
#pragma unroll
  for (int q = 0; q < 4; ++q) {
    ushort4 sv;
    sv.x = f2bf(s[q * 4 + 0]); sv.y = f2bf(s[q * 4 + 1]);
    sv.z = f2bf(s[q * 4 + 2]); sv.w = f2bf(s[q * 4 + 3]);
    *(ushort4*)(sEnd + base + q * 4) = sv;
  }
  daccv[(b * NCH + c) * NDI + d] = dacc;
}

// Phase B, IN-PLACE bf16: sp holds sEnd on entry, carry on exit.
__global__ __launch_bounds__(256) void scanB(u16* __restrict__ sp,
                                             const float* __restrict__ daccv,
                                             const float* __restrict__ Alog) {
  const int g = blockIdx.x * 256 + threadIdx.x;
  const int dn = g & (NDI * NDS - 1);
  const int b = g >> 13;
  const int d = dn >> 4, n = dn & 15;
  const float Acn = -__expf(Alog[d * NDS + n]);
  float h = 0.f;
  const long base = (long)b * NCH * NDI * NDS + dn;
  const int dbase = b * NCH * NDI + d;
  for (int c0 = 0; c0 < NCH; c0 += 32) {
    u16 pe[32]; float da[32];
#pragma unroll
    for (int j = 0; j < 32; ++j) {
      pe[j] = sp[base + (long)(c0 + j) * (NDI * NDS)];
      da[j] = daccv[dbase + (c0 + j) * NDI];
    }
#pragma unroll
    for (int j = 0; j < 32; ++j) {
      sp[base + (long)(c0 + j) * (NDI * NDS)] = f2bf(h);
      h = fmaf(__expf(Acn * da[j]), h, bf2f(pe[j]));
    }
  }
}

__global__ __launch_bounds__(256) void scanC(const u16* __restrict__ u2b,
                                             const float* __restrict__ dbc,
                                             const u16* __restrict__ xzb,
                                             const float* __restrict__ dtw,
                                             const float* __restrict__ dtbv,
                                             const float* __restrict__ Alog,
                                             const float* __restrict__ Dp,
                                             const u16* __restrict__ carry,
                                             u16* __restrict__ y) {
  const int d = ((blockIdx.x & 1) << 8) + threadIdx.x;
  const int cb = blockIdx.x >> 1;
  const int c = cb & (NCH - 1), b = cb >> NCH_LOG;
  float Ac[16], dtr[16];
#pragma unroll
  for (int q = 0; q < 4; ++q) {
    float4 v = *(const float4*)(Alog + d * NDS + q * 4);
    Ac[q * 4 + 0] = -__expf(v.x); Ac[q * 4 + 1] = -__expf(v.y);
    Ac[q * 4 + 2] = -__expf(v.z); Ac[q * 4 + 3] = -__expf(v.w);
    float4 w = *(const float4*)(dtw + d * NDR + q * 4);
    dtr[q * 4 + 0] = w.x; dtr[q * 4 + 1] = w.y; dtr[q * 4 + 2] = w.z; dtr[q * 4 + 3] = w.w;
  }
  const float dtb_d = dtbv[d];
  const float Dv = Dp[d];
  const int tbase = b * LSEQ + c * CHUNK;
  float dl[CHUNK], ul[CHUNK];
#pragma unroll
  for (int j = 0; j < CHUNK; ++j) {
    const float* row = dbc + (long)(tbase + j) * 48;
    const float4 d0 = *(const float4*)(row);
    const float4 d1 = *(const float4*)(row + 4);
    const float4 d2 = *(const float4*)(row + 8);
    const float4 d3 = *(const float4*)(row + 12);
    const float p0 = fmaf(d0.x, dtr[0], fmaf(d1.x, dtr[4], fmaf(d2.x, dtr[8],  d3.x * dtr[12])));
    const float p1 = fmaf(d0.y, dtr[1], fmaf(d1.y, dtr[5], fmaf(d2.y, dtr[9],  d3.y * dtr[13])));
    const float p2 = fmaf(d0.z, dtr[2], fmaf(d1.z, dtr[6], fmaf(d2.z, dtr[10], d3.z * dtr[14])));
    const float p3 = fmaf(d0.w, dtr[3], fmaf(d1.w, dtr[7], fmaf(d2.w, dtr[11], d3.w * dtr[15])));
    dl[j] = softplus_(dtb_d + ((p0 + p1) + (p2 + p3)));
    ul[j] = bf2f(u2b[(long)(tbase + j) * NDI + d]);
  }
  float s[16];
  const long base = ((long)((b * NCH + c) * NDI + d)) * NDS;
  {
    const bf16x8 c0v = *(const bf16x8*)(carry + base);
    const bf16x8 c1v = *(const bf16x8*)(carry + base + 8);
#pragma unroll
    for (int n = 0; n < 8; ++n) {
      s[n] = bf2f((u16)c0v[n]);
      s[8 + n] = bf2f((u16)c1v[n]);
    }
  }
#pragma unroll
  for (int j = 0; j < CHUNK; ++j) {
    const int t = tbase + j;
    const float* row = dbc + (long)t * 48 + NDR;
    const float dlj = dl[j];
    const float duj = dlj * ul[j];
    float pp[4];
#pragma unroll
    for (int q = 0; q < 4; ++q) {
      const float4 Bv = *(const float4*)(row + q * 4);
      const float4 Cq = *(const float4*)(row + NDS + q * 4);
      const float Be[4] = {Bv.x, Bv.y, Bv.z, Bv.w};
      const float Ce[4] = {Cq.x, Cq.y, Cq.z, Cq.w};
      float p = 0.f;
#pragma unroll
      for (int e = 0; e < 4; ++e) {
        const int n = q * 4 + e;
        s[n] = fmaf(__expf(dlj * Ac[n]), s[n], duj * Be[e]);
        p = fmaf(s[n], Ce[e], p);
      }
      pp[q] = p;
    }
    const float p = (pp[0] + pp[1]) + (pp[2] + pp[3]);
    const float zl = bf2f(xzb[(long)t * 1024 + NDI + d]);
    y[(long)t * NDI + d] = f2bf((p + ul[j] * Dv) * zl * sigmoidf_(zl));
  }
}

// fused final rmsnorm + mean-pool on bf16 h: block = 32 rows, wave per row
__global__ __launch_bounds__(256) void finalpool_k(const u16* __restrict__ hb,
                                                   const float* __restrict__ w,
                                                   float* __restrict__ pooled) {
  const int wave = threadIdx.x >> 6, lane = threadIdx.x & 63;
  const int t0 = blockIdx.x * 32;
  const int b = t0 >> 11;
  const float4 wv = ((const float4*)w)[lane];
  float a0 = 0.f, a1 = 0.f, a2 = 0.f, a3 = 0.f;
  for (int r = wave; r < 32; r += 4) {
    const ushort4 hv = ((const ushort4*)(hb + (long)(t0 + r) * NDM))[lane];
    const float vx = bf2f(hv.x), vy = bf2f(hv.y), vz = bf2f(hv.z), vw = bf2f(hv.w);
    float ss = vx * vx + vy * vy + vz * vz + vw * vw;
#pragma unroll
    for (int off = 32; off >= 1; off >>= 1) ss += __shfl_xor(ss, off);
    const float rs = rsqrtf(ss * (1.f / NDM) + 1e-6f);
    a0 = fmaf(vx * rs, wv.x, a0); a1 = fmaf(vy * rs, wv.y, a1);
    a2 = fmaf(vz * rs, wv.z, a2); a3 = fmaf(vw * rs, wv.w, a3);
  }
  __shared__ float red[4][NDM];
  red[wave][lane * 4 + 0] = a0; red[wave][lane * 4 + 1] = a1;
  red[wave][lane * 4 + 2] = a2; red[wave][lane * 4 + 3] = a3;
  __syncthreads();
  if (wave == 0) {
#pragma unroll
    for (int e = 0; e < 4; ++e) {
      const int dc = lane * 4 + e;
      const float sum = red[0][dc] + red[1][dc] + red[2][dc] + red[3][dc];
      atomicAdd(pooled + b * NDM + dc, sum * (1.f / LSEQ));
    }
  }
}

// out = x + bias broadcast; bias recomputed per block (pooled/proj_w are
// L2-resident; ~1us hidden work) — saves the separate bias_k launch.
// Each block covers 8 rows (256 float4), never straddling a batch.
__global__ __launch_bounds__(256) void addout_k(const float* __restrict__ x,
                                                const float* __restrict__ pooled,
                                                const float* __restrict__ pw,
                                                const float* __restrict__ pb,
                                                float* __restrict__ out) {
  __shared__ float bs[NF];
  const int wave = threadIdx.x >> 6, lane = threadIdx.x & 63;
  const int b = (blockIdx.x * 8) >> 11;
  const float4 pv = ((const float4*)(pooled + b * NDM))[lane];
#pragma unroll
  for (int f0 = 0; f0 < 32; ++f0) {
    const int f = wave * 32 + f0;
    const float4 wv = ((const float4*)(pw + f * NDM))[lane];
    float acc = pv.x * wv.x + pv.y * wv.y + pv.z * wv.z + pv.w * wv.w;
#pragma unroll
    for (int off = 32; off >= 1; off >>= 1) acc += __shfl_xor(acc, off);
    if (lane == 0) bs[f] = acc + pb[f];
  }
  __syncthreads();
  const int i4 = blockIdx.x * 256 + threadIdx.x;
  const float4 xv = ((const float4*)x)[i4];
  const int f4 = i4 & 31;
  const float4 bb = *(const float4*)(bs + f4 * 4);
  float4 o;
  o.x = xv.x + bb.x; o.y = xv.y + bb.y; o.z = xv.z + bb.z; o.w = xv.w + bb.w;
  ((float4*)out)[i4] = o;
}

extern "C" void kernel_launch(void* const* d_in, const int* in_sizes, int n_in,
                              void* d_out, int out_size, void* d_ws, size_t ws_size,
                              hipStream_t stream) {
  const float* x       = (const float*)d_in[0];
  const float* embed_w = (const float*)d_in[1];
  const float* embed_b = (const float*)d_in[2];
  const float* in_w    = (const float*)d_in[3];
  const float* conv_w  = (const float*)d_in[4];
  const float* conv_b  = (const float*)d_in[5];
  const float* xproj_w = (const float*)d_in[6];
  const float* dt_w    = (const float*)d_in[7];
  const float* dt_b    = (const float*)d_in[8];
  const float* A_log   = (const float*)d_in[9];
  const float* Dw      = (const float*)d_in[10];
  const float* out_w   = (const float*)d_in[11];
  const float* norm_w  = (const float*)d_in[12];
  const float* fnorm_w = (const float*)d_in[13];
  const float* proj_w  = (const float*)d_in[14];
  const float* proj_b  = (const float*)d_in[15];

  // workspace layout (f32 units), ~53 MB (ws = 268 MB). Full audit (R4 rule):
  float* ws      = (float*)d_ws;
  float* hbr     = ws;                     // 1,048,576 f32-eq: hb bf16 (2,097,152)
  float* xzr     = hbr  + 1048576;         // 4,194,304 f32-eq: xzb bf16 (8,388,608)
  float* u2r     = xzr  + 4194304;         // 2,097,152 f32-eq: u2b bf16 (4,194,304)
  float* ybr     = u2r  + 2097152;         // 2,097,152 f32-eq: ybb bf16 (4,194,304)
  float* dbc     = ybr  + 2097152;         // 393,216 f32
  float* sEndr   = dbc  + 393216;          // 2,097,152 f32-eq: sEnd bf16 (4,194,304)
  float* daccv   = sEndr + 2097152;        // 262,144 f32 (BATCH*NCH*NDI exactly)
  float* xbr     = daccv + 262144;         // 524,288 f32-eq: xb bf16 (1,048,576)
  float* inwr    = xbr  + 524288;          // 262,144 f32-eq: in_w' bf16
  float* owr     = inwr + 262144;          // 131,072 f32-eq: out_w bf16
  float* xpwr    = owr  + 131072;          // 24,576 f32-eq: xproj_w bf16
  float* ewr     = xpwr + 24576;           // 16,384 f32-eq: embed_w bf16
  float* pooled  = ewr  + 16384;           // 1,024   --+ zeroed by megacvt
  float* rowssq0 = pooled + 1024;          // 8,192     | (17,408 f32 = 4,352 f4)
  float* rowssq1 = rowssq0 + 8192;         // 8,192   --+

  u16* ybb  = (u16*)ybr;
  u16* hb   = (u16*)hbr;
  u16* xzb  = (u16*)xzr;
  u16* u2b  = (u16*)u2r;
  u16* sEnd = (u16*)sEndr;
  u16* xb   = (u16*)xbr;
  u16* inwb = (u16*)inwr;
  u16* owb  = (u16*)owr;
  u16* xpwb = (u16*)xpwr;
  u16* ewb  = (u16*)ewr;

  megacvt_k<<<1872, 256, 0, stream>>>(x, embed_w, in_w, out_w, xproj_w, norm_w,
                                      xb, ewb, inwb, owb, xpwb, pooled);

  // hb = bf16(x @ embed_w^T + embed_b)  (EPI=1 -> hb + rowssq0)
  gemm_bf16<128, 64, true, false, false, 1><<<dim3(4, 64), 256, 0, stream>>>(
      xb, ewb, embed_b, hb, NDM, NF, rowssq0);

  for (int i = 0; i < 2; ++i) {
    const float* cw  = conv_w + (long)i * NDI * 4;
    const float* cb  = conv_b + (long)i * NDI;
    const float* dtw = dt_w   + (long)i * NDI * NDR;
    const float* dtb = dt_b   + (long)i * NDI;
    const float* al  = A_log  + (long)i * NDI * NDS;
    const float* dd  = Dw     + (long)i * NDI;
    float* rsq       = i ? rowssq1 : rowssq0;

    // xz = rmsnorm(h) @ in_w'^T  (commuted RMS epilogue)
    gemm_bf16<128, 128, false, false, false, 2><<<dim3(8, 64), 256, 0, stream>>>(
        hb, inwb + (long)i * 2 * NDI * NDM, nullptr, xzb, 1024, NDM, rsq);
    conv_silu_k<<<TTOK / 4, 256, 0, stream>>>(xzb, cw, cb, u2b);
    // dbc = u2 @ xproj_w^T  (MFMA, 128 blocks, N=48 clamped)
    gemm_bf16<64, 64, false, false, true, 0><<<dim3(1, 128), 256, 0, stream>>>(
        u2b, xpwb + (long)i * 48 * NDI, nullptr, dbc, 48, NDI, nullptr);
    // chunked parallel scan (3 kernels; cheap sync = kernel boundary)
    scanA<<<BATCH * NCH * 2, 256, 0, stream>>>(u2b, dbc, dtw, dtb, al, sEnd, daccv);
    scanB<<<BATCH * NDI * NDS / 256, 256, 0, stream>>>(sEnd, daccv, al);
    scanC<<<BATCH * NCH * 2, 256, 0, stream>>>(u2b, dbc, xzb, dtw, dtb, al, dd,
                                               sEnd, ybb);
    // h += yb @ out_w^T (bf16 residual); L0 also emits rowssq1 (EPI=1)
    if (i == 0)
      gemm_bf16<128, 64, false, true, false, 1><<<dim3(4, 64), 256, 0, stream>>>(
          ybb, owb, nullptr, hb, NDM, NDI, rowssq1);
    else
      gemm_bf16<128, 64, false, true, false, 3><<<dim3(4, 64), 256, 0, stream>>>(
          ybb, owb + (long)NDM * NDI, nullptr, hb, NDM, NDI, nullptr);
  }

  finalpool_k<<<TTOK / 32, 256, 0, stream>>>(hb, fnorm_w, pooled);
  addout_k<<<TTOK * NF / 4 / 256, 256, 0, stream>>>(x, pooled, proj_w, proj_b,
                                                    (float*)d_out);
}

// Round 14
// 256.510 us; speedup vs baseline: 4.2443x; 1.0639x over previous
//
#include <hip/hip_runtime.h>

#define TTOK 8192   // B*L
#define BATCH 4
#define LSEQ 2048
#define NDM 256
#define NF 128
#define NDI 512
#define NDS 16
#define NDR 16
#define CHUNK 16
#define NCH (LSEQ / CHUNK)   // 128
#define NCH_LOG 7

typedef unsigned short u16;
typedef __attribute__((ext_vector_type(8))) short bf16x8;
typedef __attribute__((ext_vector_type(4))) float f32x4;

__device__ __forceinline__ float sigmoidf_(float x) { return 1.f / (1.f + __expf(-x)); }

__device__ __forceinline__ u16 f2bf(float f) {  // RTN-even
  unsigned u = __float_as_uint(f);
  u += 0x7FFF + ((u >> 16) & 1);
  return (u16)(u >> 16);
}
__device__ __forceinline__ float bf2f(u16 v) {
  return __uint_as_float((unsigned)v << 16);
}
__device__ __forceinline__ float softplus_(float x) {  // stable
  return fmaxf(x, 0.f) + __logf(1.f + __expf(-fabsf(x)));
}

// ---------------- bf16 MFMA GEMM ----------------
// C = A·W^T (+bias) (+= if RES). A:[M][K] bf16, W:[N][K] bf16.
// Tile BM_T x BN_T, BK=64, 4 waves. NCHK: clamp W rows / skip cols >= N.
// EPI: 0 = f32 out. 1 = bf16 out (+bf16 residual if RES) + per-row ssq
//      atomicAdd into rssq. 2 = "RMS": scale by rsqrt(rssq[r]/256+eps), bf16
//      out. 3 = bf16 out (+bf16 residual), plain.
// R11 lesson (permanent): no cooperative grid.sync — cross-XCD L2 flush
// costs ~450us. R12 lesson: don't replicate small-kernel work into every
// block of a big kernel to save a launch (bias-in-addout cost +15us).
template<int BM_T, int BN_T, bool BIAS, bool RES, bool NCHK, int EPI>
__global__ __launch_bounds__(256) void gemm_bf16(const u16* __restrict__ A,
                                                 const u16* __restrict__ W,
                                                 const float* __restrict__ bias,
                                                 void* __restrict__ Cv,
                                                 int N, int K,
                                                 float* __restrict__ rssq) {
  constexpr int WR = BM_T / 64;
  constexpr int WC = 4 / WR;
  constexpr int NR = BN_T / (16 * WC);
  constexpr int ROWS = BM_T + BN_T;
  constexpr int CPW = ROWS / 32;
  __shared__ u16 lds[ROWS * 64];
  const int tid = threadIdx.x;
  const int wave = tid >> 6, lane = tid & 63;
  const int wrow = wave / WC, wcol = wave % WC;
  const int lr = lane & 15, lg = lane >> 4;
  const int row0 = blockIdx.y * BM_T, col0 = blockIdx.x * BN_T;

  const u16* srcp[CPW];
  u16* ldsp[CPW];
#pragma unroll
  for (int i = 0; i < CPW; ++i) {
    const int q = wave * CPW + i;
    const int row = q * 8 + (lane >> 3);
    const int ck = lane & 7;
    const int sck = ck ^ (row & 7);
    long grow;
    if (row < BM_T) grow = (long)(row0 + row) * K;
    else {
      int wr = row - BM_T;
      if (NCHK && wr >= N) wr = N - 1;
      grow = (long)(col0 + wr) * K;
    }
    srcp[i] = ((row < BM_T) ? A : W) + grow + sck * 8;
    ldsp[i] = (u16*)&lds[q * 512];
  }

  int aoff[4], as7[4], boff[NR], bs7[NR];
#pragma unroll
  for (int m = 0; m < 4; ++m) {
    const int r = wrow * 64 + m * 16 + lr;
    aoff[m] = r * 64; as7[m] = r & 7;
  }
#pragma unroll
  for (int n = 0; n < NR; ++n) {
    const int r = BM_T + wcol * (BN_T / WC) + n * 16 + lr;
    boff[n] = r * 64; bs7[n] = r & 7;
  }

  f32x4 acc[4][NR];
#pragma unroll
  for (int m = 0; m < 4; ++m)
#pragma unroll
    for (int n = 0; n < NR; ++n) acc[m][n] = (f32x4)(0.f);

  for (int k0 = 0; k0 < K; k0 += 64) {
#pragma unroll
    for (int i = 0; i < CPW; ++i)
      __builtin_amdgcn_global_load_lds(
          (const __attribute__((address_space(1))) unsigned int*)(srcp[i] + k0),
          (__attribute__((address_space(3))) unsigned int*)(ldsp[i]), 16, 0, 0);
    __syncthreads();

    bf16x8 af[2][4], bfr[2][NR];
#pragma unroll
    for (int kq = 0; kq < 2; ++kq) {
      const int kc = kq * 4 + lg;
#pragma unroll
      for (int m = 0; m < 4; ++m)
        af[kq][m] = *(const bf16x8*)(lds + aoff[m] + ((kc ^ as7[m]) << 3));
#pragma unroll
      for (int n = 0; n < NR; ++n)
        bfr[kq][n] = *(const bf16x8*)(lds + boff[n] + ((kc ^ bs7[n]) << 3));
    }
#pragma unroll
    for (int kq = 0; kq < 2; ++kq)
#pragma unroll
      for (int m = 0; m < 4; ++m)
#pragma unroll
        for (int n = 0; n < NR; ++n)
          acc[m][n] = __builtin_amdgcn_mfma_f32_16x16x32_bf16(af[kq][m], bfr[kq][n],
                                                              acc[m][n], 0, 0, 0);
    __syncthreads();
  }

  // C/D layout: col = lane&15, row = (lane>>4)*4 + j
#pragma unroll
  for (int m = 0; m < 4; ++m) {
    const int rbase = row0 + wrow * 64 + m * 16 + lg * 4;
#pragma unroll
    for (int j = 0; j < 4; ++j) {
      const int r = rbase + j;
      if (EPI == 2) {
        const float rs = rsqrtf(rssq[r] * (1.f / 256.f) + 1e-6f);
#pragma unroll
        for (int n = 0; n < NR; ++n) {
          const int c = col0 + wcol * (BN_T / WC) + n * 16 + lr;
          ((u16*)Cv)[(long)r * N + c] = f2bf(acc[m][n][j] * rs);
        }
      } else if (EPI == 1 || EPI == 3) {
        float ssq = 0.f;
#pragma unroll
        for (int n = 0; n < NR; ++n) {
          const int c = col0 + wcol * (BN_T / WC) + n * 16 + lr;
          float v = acc[m][n][j] + (BIAS ? bias[c] : 0.f);
          const long off = (long)r * N + c;
          if (RES) v += bf2f(((u16*)Cv)[off]);
          ((u16*)Cv)[off] = f2bf(v);
          if (EPI == 1) ssq = fmaf(v, v, ssq);
        }
        if (EPI == 1) {
          ssq += __shfl_xor(ssq, 1); ssq += __shfl_xor(ssq, 2);
          ssq += __shfl_xor(ssq, 4); ssq += __shfl_xor(ssq, 8);
          if (lr == 0) atomicAdd(rssq + r, ssq);
        }
      } else {
#pragma unroll
        for (int n = 0; n < NR; ++n) {
          const int c = col0 + wcol * (BN_T / WC) + n * 16 + lr;
          if (NCHK && c >= N) continue;
          float v = acc[m][n][j] + (BIAS ? bias[c] : 0.f);
          float* p = (float*)Cv + (long)r * N + c;
          if (RES) *p += v; else *p = v;
        }
      }
    }
  }
}

// one-shot conversion of x + all weights to bf16; norm_w folded into in_w.
// Also zeroes pooled+rowssq (first 4352 float4s at zb).
__global__ __launch_bounds__(256) void megacvt_k(
    const float* __restrict__ x, const float* __restrict__ ew,
    const float* __restrict__ iw, const float* __restrict__ ow,
    const float* __restrict__ xw, const float* __restrict__ nw,
    u16* __restrict__ xb, u16* __restrict__ ewb, u16* __restrict__ iwb,
    u16* __restrict__ owb, u16* __restrict__ xwb, float* __restrict__ zb) {
  int i = blockIdx.x * 256 + threadIdx.x;
  if (i < 4352) ((float4*)zb)[i] = make_float4(0.f, 0.f, 0.f, 0.f);
  float4 v;
  u16* d; int di;
  if (i < 262144) { v = ((const float4*)x)[i]; d = xb; di = i; }
  else if ((i -= 262144) < 8192) { v = ((const float4*)ew)[i]; d = ewb; di = i; }
  else if ((i -= 8192) < 131072) {
    v = ((const float4*)iw)[i];
    const int layer = i >> 16;
    const float4 g = *(const float4*)(nw + layer * NDM + ((i & 63) << 2));
    v.x *= g.x; v.y *= g.y; v.z *= g.z; v.w *= g.w;
    d = iwb; di = i;
  }
  else if ((i -= 131072) < 65536) { v = ((const float4*)ow)[i]; d = owb; di = i; }
  else { i -= 65536; v = ((const float4*)xw)[i]; d = xwb; di = i; }
  ushort4 o;
  o.x = f2bf(v.x); o.y = f2bf(v.y); o.z = f2bf(v.z); o.w = f2bf(v.w);
  ((ushort4*)d)[di] = o;
}

// u2 = silu(depthwise causal conv(u)); bf16 in/out; 4 t-rows per block
__global__ __launch_bounds__(256) void conv_silu_k(const u16* __restrict__ xzb,
                                                   const float* __restrict__ cw,
                                                   const float* __restrict__ cb,
                                                   u16* __restrict__ u2b) {
  const int t0 = blockIdx.x * 4;
  const int l0 = t0 & (LSEQ - 1);
#pragma unroll
  for (int half = 0; half < 2; ++half) {
    const int ch = threadIdx.x + half * 256;
    const float w0 = cw[ch * 4], w1 = cw[ch * 4 + 1];
    const float w2 = cw[ch * 4 + 2], w3 = cw[ch * 4 + 3];
    const float bias = cb[ch];
    float v[7];
#pragma unroll
    for (int m = 0; m < 7; ++m) {
      const int tt = t0 - 3 + m;
      v[m] = (tt >= 0) ? bf2f(xzb[(long)tt * 1024 + ch]) : 0.f;
    }
#pragma unroll
    for (int j = 0; j < 4; ++j) {
      const int l = l0 + j;
      float acc = bias;
      if (l >= 3) acc = fmaf(v[j + 0], w0, acc);
      if (l >= 2) acc = fmaf(v[j + 1], w1, acc);
      if (l >= 1) acc = fmaf(v[j + 2], w2, acc);
      acc = fmaf(v[j + 3], w3, acc);
      u2b[(long)(t0 + j) * NDI + ch] = f2bf(acc * sigmoidf_(acc));
    }
  }
}

// ---- chunked parallel scan, thread-per-(b,c,d), 16 states in regs.
// 3-kernel path (R11: cooperative fusion is 4x WORSE — grid.sync flushes L2).

__global__ __launch_bounds__(256) void scanA(const u16* __restrict__ u2b,
                                             const float* __restrict__ dbc,
                                             const float* __restrict__ dtw,
                                             const float* __restrict__ dtbv,
                                             const float* __restrict__ Alog,
                                             u16* __restrict__ sEnd,
                                             float* __restrict__ daccv) {
  const int d = ((blockIdx.x & 1) << 8) + threadIdx.x;
  const int cb = blockIdx.x >> 1;
  const int c = cb & (NCH - 1), b = cb >> NCH_LOG;
  float Ac[16], dtr[16];
#pragma unroll
  for (int q = 0; q < 4; ++q) {
    float4 v = *(const float4*)(Alog + d * NDS + q * 4);
    Ac[q * 4 + 0] = -__expf(v.x); Ac[q * 4 + 1] = -__expf(v.y);
    Ac[q * 4 + 2] = -__expf(v.z); Ac[q * 4 + 3] = -__expf(v.w);
    float4 w = *(const float4*)(dtw + d * NDR + q * 4);
    dtr[q * 4 + 0] = w.x; dtr[q * 4 + 1] = w.y; dtr[q * 4 + 2] = w.z; dtr[q * 4 + 3] = w.w;
  }
  const float dtb_d = dtbv[d];
  const int tbase = b * LSEQ + c * CHUNK;
  float dl[CHUNK], du[CHUNK];
#pragma unroll
  for (int j = 0; j < CHUNK; ++j) {
    const float* row = dbc + (long)(tbase + j) * 48;
    const float4 d0 = *(const float4*)(row);
    const float4 d1 = *(const float4*)(row + 4);
    const float4 d2 = *(const float4*)(row + 8);
    const float4 d3 = *(const float4*)(row + 12);
    const float p0 = fmaf(d0.x, dtr[0], fmaf(d1.x, dtr[4], fmaf(d2.x, dtr[8],  d3.x * dtr[12])));
    const float p1 = fmaf(d0.y, dtr[1], fmaf(d1.y, dtr[5], fmaf(d2.y, dtr[9],  d3.y * dtr[13])));
    const float p2 = fmaf(d0.z, dtr[2], fmaf(d1.z, dtr[6], fmaf(d2.z, dtr[10], d3.z * dtr[14])));
    const float p3 = fmaf(d0.w, dtr[3], fmaf(d1.w, dtr[7], fmaf(d2.w, dtr[11], d3.w * dtr[15])));
    dl[j] = softplus_(dtb_d + ((p0 + p1) + (p2 + p3)));
    du[j] = dl[j] * bf2f(u2b[(long)(tbase + j) * NDI + d]);
  }
  float dacc = 0.f;
#pragma unroll
  for (int j = 0; j < CHUNK; ++j) dacc += dl[j];
  float s[16] = {};
#pragma unroll
  for (int j = 0; j < CHUNK; ++j) {
    const float* row = dbc + (long)(tbase + j) * 48 + NDR;
    const float dlj = dl[j], duj = du[j];
#pragma unroll
    for (int q = 0; q < 4; ++q) {
      const float4 Bv = *(const float4*)(row + q * 4);
      const float Be[4] = {Bv.x, Bv.y, Bv.z, Bv.w};
#pragma unroll
      for (int e = 0; e < 4; ++e) {
        const int n = q * 4 + e;
        s[n] = fmaf(__expf(dlj * Ac[n]), s[n], duj * Be[e]);
      }
    }
  }
  const long base = ((long)((b * NCH + c) * NDI + d)) * NDS;
#pragma unroll
  for (int q = 0; q < 4; ++q) {
    ushort4 sv;
    sv.x = f2bf(s[q * 4 + 0]); sv.y = f2bf(s[q * 4 + 1]);
    sv.z = f2bf(s[q * 4 + 2]); sv.w = f2bf(s[q * 4 + 3]);
    *(ushort4*)(sEnd + base + q * 4) = sv;
  }
  daccv[(b * NCH + c) * NDI + d] = dacc;
}

// Phase B, IN-PLACE bf16: sp holds sEnd on entry, carry on exit.
// 64-thread blocks x 512 blocks: parallelism is fixed at 32K threads, so
// spread them over ALL 256 CUs (128x256 left half the GPU idle).
__global__ __launch_bounds__(64) void scanB(u16* __restrict__ sp,
                                            const float* __restrict__ daccv,
                                            const float* __restrict__ Alog) {
  const int g = blockIdx.x * 64 + threadIdx.x;
  const int dn = g & (NDI * NDS - 1);
  const int b = g >> 13;
  const int d = dn >> 4, n = dn & 15;
  const float Acn = -__expf(Alog[d * NDS + n]);
  float h = 0.f;
  const long base = (long)b * NCH * NDI * NDS + dn;
  const int dbase = b * NCH * NDI + d;
  for (int c0 = 0; c0 < NCH; c0 += 32) {
    u16 pe[32]; float da[32];
#pragma unroll
    for (int j = 0; j < 32; ++j) {
      pe[j] = sp[base + (long)(c0 + j) * (NDI * NDS)];
      da[j] = daccv[dbase + (c0 + j) * NDI];
    }
#pragma unroll
    for (int j = 0; j < 32; ++j) {
      sp[base + (long)(c0 + j) * (NDI * NDS)] = f2bf(h);
      h = fmaf(__expf(Acn * da[j]), h, bf2f(pe[j]));
    }
  }
}

__global__ __launch_bounds__(256) void scanC(const u16* __restrict__ u2b,
                                             const float* __restrict__ dbc,
                                             const u16* __restrict__ xzb,
                                             const float* __restrict__ dtw,
                                             const float* __restrict__ dtbv,
                                             const float* __restrict__ Alog,
                                             const float* __restrict__ Dp,
                                             const u16* __restrict__ carry,
                                             u16* __restrict__ y) {
  const int d = ((blockIdx.x & 1) << 8) + threadIdx.x;
  const int cb = blockIdx.x >> 1;
  const int c = cb & (NCH - 1), b = cb >> NCH_LOG;
  float Ac[16], dtr[16];
#pragma unroll
  for (int q = 0; q < 4; ++q) {
    float4 v = *(const float4*)(Alog + d * NDS + q * 4);
    Ac[q * 4 + 0] = -__expf(v.x); Ac[q * 4 + 1] = -__expf(v.y);
    Ac[q * 4 + 2] = -__expf(v.z); Ac[q * 4 + 3] = -__expf(v.w);
    float4 w = *(const float4*)(dtw + d * NDR + q * 4);
    dtr[q * 4 + 0] = w.x; dtr[q * 4 + 1] = w.y; dtr[q * 4 + 2] = w.z; dtr[q * 4 + 3] = w.w;
  }
  const float dtb_d = dtbv[d];
  const float Dv = Dp[d];
  const int tbase = b * LSEQ + c * CHUNK;
  float dl[CHUNK], ul[CHUNK];
#pragma unroll
  for (int j = 0; j < CHUNK; ++j) {
    const float* row = dbc + (long)(tbase + j) * 48;
    const float4 d0 = *(const float4*)(row);
    const float4 d1 = *(const float4*)(row + 4);
    const float4 d2 = *(const float4*)(row + 8);
    const float4 d3 = *(const float4*)(row + 12);
    const float p0 = fmaf(d0.x, dtr[0], fmaf(d1.x, dtr[4], fmaf(d2.x, dtr[8],  d3.x * dtr[12])));
    const float p1 = fmaf(d0.y, dtr[1], fmaf(d1.y, dtr[5], fmaf(d2.y, dtr[9],  d3.y * dtr[13])));
    const float p2 = fmaf(d0.z, dtr[2], fmaf(d1.z, dtr[6], fmaf(d2.z, dtr[10], d3.z * dtr[14])));
    const float p3 = fmaf(d0.w, dtr[3], fmaf(d1.w, dtr[7], fmaf(d2.w, dtr[11], d3.w * dtr[15])));
    dl[j] = softplus_(dtb_d + ((p0 + p1) + (p2 + p3)));
    ul[j] = bf2f(u2b[(long)(tbase + j) * NDI + d]);
  }
  float s[16];
  const long base = ((long)((b * NCH + c) * NDI + d)) * NDS;
  {
    const bf16x8 c0v = *(const bf16x8*)(carry + base);
    const bf16x8 c1v = *(const bf16x8*)(carry + base + 8);
#pragma unroll
    for (int n = 0; n < 8; ++n) {
      s[n] = bf2f((u16)c0v[n]);
      s[8 + n] = bf2f((u16)c1v[n]);
    }
  }
#pragma unroll
  for (int j = 0; j < CHUNK; ++j) {
    const int t = tbase + j;
    const float* row = dbc + (long)t * 48 + NDR;
    const float dlj = dl[j];
    const float duj = dlj * ul[j];
    float pp[4];
#pragma unroll
    for (int q = 0; q < 4; ++q) {
      const float4 Bv = *(const float4*)(row + q * 4);
      const float4 Cq = *(const float4*)(row + NDS + q * 4);
      const float Be[4] = {Bv.x, Bv.y, Bv.z, Bv.w};
      const float Ce[4] = {Cq.x, Cq.y, Cq.z, Cq.w};
      float p = 0.f;
#pragma unroll
      for (int e = 0; e < 4; ++e) {
        const int n = q * 4 + e;
        s[n] = fmaf(__expf(dlj * Ac[n]), s[n], duj * Be[e]);
        p = fmaf(s[n], Ce[e], p);
      }
      pp[q] = p;
    }
    const float p = (pp[0] + pp[1]) + (pp[2] + pp[3]);
    const float zl = bf2f(xzb[(long)t * 1024 + NDI + d]);
    y[(long)t * NDI + d] = f2bf((p + ul[j] * Dv) * zl * sigmoidf_(zl));
  }
}

// fused final rmsnorm + mean-pool on bf16 h: block = 32 rows, wave per row
__global__ __launch_bounds__(256) void finalpool_k(const u16* __restrict__ hb,
                                                   const float* __restrict__ w,
                                                   float* __restrict__ pooled) {
  const int wave = threadIdx.x >> 6, lane = threadIdx.x & 63;
  const int t0 = blockIdx.x * 32;
  const int b = t0 >> 11;
  const float4 wv = ((const float4*)w)[lane];
  float a0 = 0.f, a1 = 0.f, a2 = 0.f, a3 = 0.f;
  for (int r = wave; r < 32; r += 4) {
    const ushort4 hv = ((const ushort4*)(hb + (long)(t0 + r) * NDM))[lane];
    const float vx = bf2f(hv.x), vy = bf2f(hv.y), vz = bf2f(hv.z), vw = bf2f(hv.w);
    float ss = vx * vx + vy * vy + vz * vz + vw * vw;
#pragma unroll
    for (int off = 32; off >= 1; off >>= 1) ss += __shfl_xor(ss, off);
    const float rs = rsqrtf(ss * (1.f / NDM) + 1e-6f);
    a0 = fmaf(vx * rs, wv.x, a0); a1 = fmaf(vy * rs, wv.y, a1);
    a2 = fmaf(vz * rs, wv.z, a2); a3 = fmaf(vw * rs, wv.w, a3);
  }
  __shared__ float red[4][NDM];
  red[wave][lane * 4 + 0] = a0; red[wave][lane * 4 + 1] = a1;
  red[wave][lane * 4 + 2] = a2; red[wave][lane * 4 + 3] = a3;
  __syncthreads();
  if (wave == 0) {
#pragma unroll
    for (int e = 0; e < 4; ++e) {
      const int dc = lane * 4 + e;
      const float sum = red[0][dc] + red[1][dc] + red[2][dc] + red[3][dc];
      atomicAdd(pooled + b * NDM + dc, sum * (1.f / LSEQ));
    }
  }
}

// one wave per (b,f) pair: lane-parallel 256-len dot + shuffle reduce.
// 512 blocks x 64 threads so all CUs participate.
__global__ __launch_bounds__(64) void bias_k(const float* __restrict__ pooled,
                                             const float* __restrict__ pw,
                                             const float* __restrict__ pb,
                                             float* __restrict__ bv) {
  const int w = blockIdx.x;            // 512 (b,f) pairs
  const int lane = threadIdx.x;
  const int b = w >> 7, f = w & 127;
  const float4 pv = ((const float4*)(pooled + b * NDM))[lane];
  const float4 wv = ((const float4*)(pw + f * NDM))[lane];
  float acc = pv.x * wv.x + pv.y * wv.y + pv.z * wv.z + pv.w * wv.w;
#pragma unroll
  for (int off = 32; off >= 1; off >>= 1) acc += __shfl_xor(acc, off);
  if (lane == 0) bv[b * NF + f] = acc + pb[f];
}

__global__ __launch_bounds__(256) void addout_k(const float* __restrict__ x,
                                                const float* __restrict__ bv,
                                                float* __restrict__ out) {
  const int i4 = blockIdx.x * 256 + threadIdx.x;
  const float4 xv = ((const float4*)x)[i4];
  const int trow = i4 >> 5;
  const int b = trow >> 11;
  const int f4 = i4 & 31;
  const float4 bb = ((const float4*)bv)[b * 32 + f4];
  float4 o;
  o.x = xv.x + bb.x; o.y = xv.y + bb.y; o.z = xv.z + bb.z; o.w = xv.w + bb.w;
  ((float4*)out)[i4] = o;
}

extern "C" void kernel_launch(void* const* d_in, const int* in_sizes, int n_in,
                              void* d_out, int out_size, void* d_ws, size_t ws_size,
                              hipStream_t stream) {
  const float* x       = (const float*)d_in[0];
  const float* embed_w = (const float*)d_in[1];
  const float* embed_b = (const float*)d_in[2];
  const float* in_w    = (const float*)d_in[3];
  const float* conv_w  = (const float*)d_in[4];
  const float* conv_b  = (const float*)d_in[5];
  const float* xproj_w = (const float*)d_in[6];
  const float* dt_w    = (const float*)d_in[7];
  const float* dt_b    = (const float*)d_in[8];
  const float* A_log   = (const float*)d_in[9];
  const float* Dw      = (const float*)d_in[10];
  const float* out_w   = (const float*)d_in[11];
  const float* norm_w  = (const float*)d_in[12];
  const float* fnorm_w = (const float*)d_in[13];
  const float* proj_w  = (const float*)d_in[14];
  const float* proj_b  = (const float*)d_in[15];

  // workspace layout (f32 units), ~53 MB (ws = 268 MB). Full audit (R4 rule):
  float* ws      = (float*)d_ws;
  float* hbr     = ws;                     // 1,048,576 f32-eq: hb bf16 (2,097,152)
  float* xzr     = hbr  + 1048576;         // 4,194,304 f32-eq: xzb bf16 (8,388,608)
  float* u2r     = xzr  + 4194304;         // 2,097,152 f32-eq: u2b bf16 (4,194,304)
  float* ybr     = u2r  + 2097152;         // 2,097,152 f32-eq: ybb bf16 (4,194,304)
  float* dbc     = ybr  + 2097152;         // 393,216 f32
  float* sEndr   = dbc  + 393216;          // 2,097,152 f32-eq: sEnd bf16 (4,194,304)
  float* daccv   = sEndr + 2097152;        // 262,144 f32 (BATCH*NCH*NDI exactly)
  float* xbr     = daccv + 262144;         // 524,288 f32-eq: xb bf16 (1,048,576)
  float* inwr    = xbr  + 524288;          // 262,144 f32-eq: in_w' bf16
  float* owr     = inwr + 262144;          // 131,072 f32-eq: out_w bf16
  float* xpwr    = owr  + 131072;          // 24,576 f32-eq: xproj_w bf16
  float* ewr     = xpwr + 24576;           // 16,384 f32-eq: embed_w bf16
  float* pooled  = ewr  + 16384;           // 1,024   --+ zeroed by megacvt
  float* rowssq0 = pooled + 1024;          // 8,192     | (17,408 f32 = 4,352 f4)
  float* rowssq1 = rowssq0 + 8192;         // 8,192   --+
  float* bv      = rowssq1 + 8192;         // 512

  u16* ybb  = (u16*)ybr;
  u16* hb   = (u16*)hbr;
  u16* xzb  = (u16*)xzr;
  u16* u2b  = (u16*)u2r;
  u16* sEnd = (u16*)sEndr;
  u16* xb   = (u16*)xbr;
  u16* inwb = (u16*)inwr;
  u16* owb  = (u16*)owr;
  u16* xpwb = (u16*)xpwr;
  u16* ewb  = (u16*)ewr;

  megacvt_k<<<1872, 256, 0, stream>>>(x, embed_w, in_w, out_w, xproj_w, norm_w,
                                      xb, ewb, inwb, owb, xpwb, pooled);

  // hb = bf16(x @ embed_w^T + embed_b)  (EPI=1 -> hb + rowssq0)
  gemm_bf16<128, 64, true, false, false, 1><<<dim3(4, 64), 256, 0, stream>>>(
      xb, ewb, embed_b, hb, NDM, NF, rowssq0);

  for (int i = 0; i < 2; ++i) {
    const float* cw  = conv_w + (long)i * NDI * 4;
    const float* cb  = conv_b + (long)i * NDI;
    const float* dtw = dt_w   + (long)i * NDI * NDR;
    const float* dtb = dt_b   + (long)i * NDI;
    const float* al  = A_log  + (long)i * NDI * NDS;
    const float* dd  = Dw     + (long)i * NDI;
    float* rsq       = i ? rowssq1 : rowssq0;

    // xz = rmsnorm(h) @ in_w'^T  (commuted RMS epilogue)
    gemm_bf16<128, 128, false, false, false, 2><<<dim3(8, 64), 256, 0, stream>>>(
        hb, inwb + (long)i * 2 * NDI * NDM, nullptr, xzb, 1024, NDM, rsq);
    conv_silu_k<<<TTOK / 4, 256, 0, stream>>>(xzb, cw, cb, u2b);
    // dbc = u2 @ xproj_w^T  (MFMA, 128 blocks, N=48 clamped)
    gemm_bf16<64, 64, false, false, true, 0><<<dim3(1, 128), 256, 0, stream>>>(
        u2b, xpwb + (long)i * 48 * NDI, nullptr, dbc, 48, NDI, nullptr);
    // chunked parallel scan (3 kernels; cheap sync = kernel boundary)
    scanA<<<BATCH * NCH * 2, 256, 0, stream>>>(u2b, dbc, dtw, dtb, al, sEnd, daccv);
    scanB<<<BATCH * NDI * NDS / 64, 64, 0, stream>>>(sEnd, daccv, al);
    scanC<<<BATCH * NCH * 2, 256, 0, stream>>>(u2b, dbc, xzb, dtw, dtb, al, dd,
                                               sEnd, ybb);
    // h += yb @ out_w^T (bf16 residual); L0 also emits rowssq1 (EPI=1)
    if (i == 0)
      gemm_bf16<128, 64, false, true, false, 1><<<dim3(4, 64), 256, 0, stream>>>(
          ybb, owb, nullptr, hb, NDM, NDI, rowssq1);
    else
      gemm_bf16<128, 64, false, true, false, 3><<<dim3(4, 64), 256, 0, stream>>>(
          ybb, owb + (long)NDM * NDI, nullptr, hb, NDM, NDI, nullptr);
  }

  finalpool_k<<<TTOK / 32, 256, 0, stream>>>(hb, fnorm_w, pooled);
  bias_k<<<512, 64, 0, stream>>>(pooled, proj_w, proj_b, bv);
  addout_k<<<TTOK * NF / 4 / 256, 256, 0, stream>>>(x, bv, (float*)d_out);
}